// Round 9
// baseline (1429.470 us; speedup 1.0000x reference)
//
#include <hip/hip_runtime.h>
#include <math.h>

#define NU      256
#define NLAYERS 6
#define NBATCH  32768
#define NDIN    784
#define NDOUT   10
#define NUSQ    65536

typedef unsigned short u16;
typedef __attribute__((ext_vector_type(8))) short s16x8;
typedef __attribute__((ext_vector_type(4))) float f32x4;

// bf16 helpers (RNE)
__device__ __forceinline__ u16 f2bf(float x) {
    union { float f; unsigned u; } a; a.f = x;
    const unsigned r = a.u + 0x7fffu + ((a.u >> 16) & 1u);
    return (u16)(r >> 16);
}
__device__ __forceinline__ float bf2f(u16 h) {
    union { unsigned u; float f; } a; a.u = ((unsigned)h) << 16; return a.f;
}
__device__ __forceinline__ float rdlane(float v, int lane) {
    return __uint_as_float(__builtin_amdgcn_readlane(__float_as_uint(v), lane));
}

// async global->LDS, 16 B per lane
__device__ __forceinline__ void gl_lds16(const u16* g, u16* l) {
    __builtin_amdgcn_global_load_lds(
        (const __attribute__((address_space(1))) void*)g,
        (__attribute__((address_space(3))) void*)l, 16, 0, 0);
}

// 32-way static-index dispatch over a wave-uniform column index.
#define COL_CASES(BODY) \
    case 0:  BODY(0);  break; case 1:  BODY(1);  break; \
    case 2:  BODY(2);  break; case 3:  BODY(3);  break; \
    case 4:  BODY(4);  break; case 5:  BODY(5);  break; \
    case 6:  BODY(6);  break; case 7:  BODY(7);  break; \
    case 8:  BODY(8);  break; case 9:  BODY(9);  break; \
    case 10: BODY(10); break; case 11: BODY(11); break; \
    case 12: BODY(12); break; case 13: BODY(13); break; \
    case 14: BODY(14); break; case 15: BODY(15); break; \
    case 16: BODY(16); break; case 17: BODY(17); break; \
    case 18: BODY(18); break; case 19: BODY(19); break; \
    case 20: BODY(20); break; case 21: BODY(21); break; \
    case 22: BODY(22); break; case 23: BODY(23); break; \
    case 24: BODY(24); break; case 25: BODY(25); break; \
    case 26: BODY(26); break; case 27: BODY(27); break; \
    case 28: BODY(28); break; case 29: BODY(29); break; \
    case 30: BODY(30); break; case 31: BODY(31); break;

// ---------------------------------------------------------------------------
// Fused first kernel: blocks 0..5 = GJ inversion; blocks 6..261 = in_gemm
// (128-row stripe x BOTH 128-col tiles, all 512 threads active, shared As).
//
// Invert phase B rewritten register-light (round-9): no t[32]/prw[32] temp
// arrays (they forced AGPR/scratch churn at the 128-VGPR target for 3
// rounds). Per column i: readlane (scalar lane idx -> no LDS) + 4 FMA +
// predicated pivot-row overwrite. Column-k result written exactly in a
// post-pass (algebraically identical to the proven ZCOL-before-FMA order).
// ---------------------------------------------------------------------------
__global__ __launch_bounds__(512, 2) void fused_inv_ingemm(
    const float* __restrict__ B0, const float* __restrict__ qg,
    u16* __restrict__ wnnh, u16* __restrict__ wnnl,
    u16* __restrict__ wnth, u16* __restrict__ wntl,
    float* __restrict__ bq,
    const float* __restrict__ X, const float* __restrict__ Win,
    const float* __restrict__ bin,
    u16* __restrict__ V0h, u16* __restrict__ V0l,
    u16* __restrict__ V1h, u16* __restrict__ V1l)
{
    // ---- invert LDS ----
    __shared__ __align__(16) float colv[2][256];
    __shared__ int   s_p[2];
    __shared__ float s_pv[2];
    __shared__ int   pivrow[256];
    __shared__ int   ilogrow[256];
    __shared__ float qs[256];
    __shared__ float part[8][256];
    // ---- in_gemm LDS ----
    __shared__ __align__(16) float As[16][128];
    __shared__ __align__(16) float Bs[2][16][128];

    const int tid = threadIdx.x;

    if (blockIdx.x < NLAYERS) {
        // =================== inversion path ===================
        const int layer = blockIdx.x;
        const int ct = tid & 63;     // lane: owns rows ct*4 .. ct*4+3
        const int wv = tid >> 6;     // wave: owns cols wv*32 .. wv*32+31

        float a[32][4];
        const float* Ablk = B0 + (size_t)layer * NU * NU;
#pragma unroll
        for (int j = 0; j < 4; ++j) {
            const float* rp = Ablk + (size_t)(ct*4 + j)*NU + wv*32;
#pragma unroll
            for (int i = 0; i < 32; i += 4) {
                const float4 v = *(const float4*)(rp + i);
                a[i+0][j] = v.x; a[i+1][j] = v.y; a[i+2][j] = v.z; a[i+3][j] = v.w;
            }
        }

        int used = 0;

        for (int k = 0; k < 256; ++k) {
            const int wvk = k >> 5, ikk = k & 31, buf = k & 1;

            // ---- Phase A: column owner finds pivot + snapshots column ----
            if (wv == wvk) {
                float c0, c1, c2, c3;
#define EXT(I) { c0 = a[I][0]; c1 = a[I][1]; c2 = a[I][2]; c3 = a[I][3]; }
                switch (ikk) { COL_CASES(EXT) }
#undef EXT
                float ba = -1.0f, bv = 1.0f; int br = 0;
                {
                    float av;
                    av = (used & 1) ? -1.0f : fabsf(c0);
                    if (av > ba) { ba = av; bv = c0; br = ct*4 + 0; }
                    av = (used & 2) ? -1.0f : fabsf(c1);
                    if (av > ba) { ba = av; bv = c1; br = ct*4 + 1; }
                    av = (used & 4) ? -1.0f : fabsf(c2);
                    if (av > ba) { ba = av; bv = c2; br = ct*4 + 2; }
                    av = (used & 8) ? -1.0f : fabsf(c3);
                    if (av > ba) { ba = av; bv = c3; br = ct*4 + 3; }
                }
#pragma unroll
                for (int off = 32; off > 0; off >>= 1) {
                    const float oa = __shfl_down(ba, off);
                    const float ov = __shfl_down(bv, off);
                    const int   orr = __shfl_down(br, off);
                    if (oa > ba) { ba = oa; bv = ov; br = orr; }
                }
                float4 cw; cw.x = c0; cw.y = c1; cw.z = c2; cw.w = c3;
                *(float4*)(&colv[buf][ct*4]) = cw;
                if (ct == 0) {
                    s_p[buf] = br;
                    s_pv[buf] = 1.0f / bv;
                    pivrow[k] = br;
                }
            }
            __syncthreads();

            // ---- Phase B: rank-1 elimination (register-light) ----
            const int   p      = __builtin_amdgcn_readfirstlane(s_p[buf]);
            const float pivinv = s_pv[buf];
            const int ctp = p >> 2, jp = p & 3;
            const bool mine = (ct == ctp);

            const float4 dv = *(const float4*)(&colv[buf][ct*4]);
            const float e0 = -dv.x, e1 = -dv.y, e2 = -dv.z, e3 = -dv.w;

#define ELIM(JP) { _Pragma("unroll") for (int i = 0; i < 32; ++i) { \
                const float c  = rdlane(a[i][JP], ctp); \
                const float pv = c * pivinv; \
                const float r0 = fmaf(e0, pv, a[i][0]); \
                const float r1 = fmaf(e1, pv, a[i][1]); \
                const float r2 = fmaf(e2, pv, a[i][2]); \
                const float r3 = fmaf(e3, pv, a[i][3]); \
                a[i][0] = (mine && JP == 0) ? pv : r0; \
                a[i][1] = (mine && JP == 1) ? pv : r1; \
                a[i][2] = (mine && JP == 2) ? pv : r2; \
                a[i][3] = (mine && JP == 3) ? pv : r3; } }
            switch (jp) {
                case 0: ELIM(0) break; case 1: ELIM(1) break;
                case 2: ELIM(2) break; default: ELIM(3) break;
            }
#undef ELIM

            // column-k exact result (owning wave only; ikk is wave-local)
            if (wv == wvk) {
#define ZFIX(I) { \
                a[I][0] = (mine && jp == 0) ? pivinv : e0 * pivinv; \
                a[I][1] = (mine && jp == 1) ? pivinv : e1 * pivinv; \
                a[I][2] = (mine && jp == 2) ? pivinv : e2 * pivinv; \
                a[I][3] = (mine && jp == 3) ? pivinv : e3 * pivinv; }
                switch (ikk) { COL_CASES(ZFIX) }
#undef ZFIX
            }
            if (mine) used |= (1 << jp);
        }
        __syncthreads();

        // stored a[i][j] = M[r][c], r = ilog[ct*4+j], c = pivrow[wv*32+i]
        if (tid < 256) { ilogrow[pivrow[tid]] = tid; qs[tid] = qg[(size_t)layer*NU + tid]; }
        __syncthreads();

        // ---- bq = M q ----
        {
            float s0=0.f, s1=0.f, s2=0.f, s3=0.f;
#pragma unroll
            for (int i = 0; i < 32; ++i) {
                const float qq = qs[pivrow[wv*32 + i]];
                s0 = fmaf(a[i][0], qq, s0);
                s1 = fmaf(a[i][1], qq, s1);
                s2 = fmaf(a[i][2], qq, s2);
                s3 = fmaf(a[i][3], qq, s3);
            }
            part[wv][ct*4+0] = s0; part[wv][ct*4+1] = s1;
            part[wv][ct*4+2] = s2; part[wv][ct*4+3] = s3;
        }
        __syncthreads();
        if (tid < 256) {
            float s = 0.f;
#pragma unroll
            for (int w2 = 0; w2 < 8; ++w2) s += part[w2][tid];
            bq[(size_t)layer*NU + ilogrow[tid]] = s;
        }

        // ---- split-bf16 W planes ----
        u16* nh = wnnh + (size_t)layer*NUSQ; u16* nl = wnnl + (size_t)layer*NUSQ;
        u16* th = wnth + (size_t)layer*NUSQ; u16* tl = wntl + (size_t)layer*NUSQ;
#pragma unroll
        for (int j = 0; j < 4; ++j) {
            const int r = ilogrow[ct*4 + j];
#pragma unroll
            for (int i = 0; i < 32; ++i) {
                const int c = pivrow[wv*32 + i];
                const float v = a[i][j];
                const u16 h  = f2bf(v);
                const u16 lo = f2bf(v - bf2f(h));
                th[(size_t)r*NU + c] = h;  tl[(size_t)r*NU + c] = lo;
                nh[(size_t)c*NU + r] = h;  nl[(size_t)c*NU + r] = lo;
            }
        }
        return;
    }

    // ========== in_gemm path: 512 threads, one 128-row stripe, both n-tiles ==========
    const int bid  = blockIdx.x - NLAYERS;    // 0..255
    const int m0   = bid * 128;
    const int half = tid >> 8;                // 0/1 -> n-tile
    const int t2   = tid & 255;
    const int n0   = half * 128;
    const int tx = t2 & 15, ty = t2 >> 4;
    const int K = NDIN;

    float acc[8][8];
#pragma unroll
    for (int i = 0; i < 8; ++i)
#pragma unroll
        for (int j = 0; j < 8; ++j) acc[i][j] = 0.0f;

    const int am = t2 >> 1;
    const int ak = (t2 & 1) * 8;
    const int bk = t2 >> 4;
    const int bn = (t2 & 15) * 8;

    for (int k0 = 0; k0 < K; k0 += 16) {
        if (half == 0) {      // As shared by both halves
            const float* Ap = X + (size_t)(m0 + am)*K + (k0 + ak);
            const float4 a0 = *(const float4*)(Ap);
            const float4 a1 = *(const float4*)(Ap + 4);
            As[ak+0][am] = a0.x; As[ak+1][am] = a0.y; As[ak+2][am] = a0.z; As[ak+3][am] = a0.w;
            As[ak+4][am] = a1.x; As[ak+5][am] = a1.y; As[ak+6][am] = a1.z; As[ak+7][am] = a1.w;
        }
        {
            const float* Bp = Win + (size_t)(k0 + bk)*NU + (n0 + bn);
            const float4 b0 = *(const float4*)(Bp);
            const float4 b1 = *(const float4*)(Bp + 4);
            *(float4*)(&Bs[half][bk][bn])   = b0;
            *(float4*)(&Bs[half][bk][bn+4]) = b1;
        }
        __syncthreads();
#pragma unroll
        for (int kk = 0; kk < 16; ++kk) {
            float af[8], bf[8];
            *(float4*)(af)   = *(const float4*)(&As[kk][ty*8]);
            *(float4*)(af+4) = *(const float4*)(&As[kk][ty*8+4]);
            *(float4*)(bf)   = *(const float4*)(&Bs[half][kk][tx*8]);
            *(float4*)(bf+4) = *(const float4*)(&Bs[half][kk][tx*8+4]);
#pragma unroll
            for (int i = 0; i < 8; ++i)
#pragma unroll
                for (int j = 0; j < 8; ++j)
                    acc[i][j] = fmaf(af[i], bf[j], acc[i][j]);
        }
        __syncthreads();
    }

#pragma unroll
    for (int i = 0; i < 8; ++i) {
        const size_t row = m0 + ty*8 + i;
        s16x8 vh, vl, th2, tl2;
#pragma unroll
        for (int j = 0; j < 8; ++j) {
            const float v = acc[i][j] + bin[n0 + tx*8 + j];
            const u16 h  = f2bf(v);
            vh[j] = (short)h; vl[j] = (short)f2bf(v - bf2f(h));
            const float tv = tanhf(v);
            const u16 h2 = f2bf(tv);
            th2[j] = (short)h2; tl2[j] = (short)f2bf(tv - bf2f(h2));
        }
        const size_t o = row*NU + n0 + tx*8;
        *(s16x8*)&V0h[o] = vh;  *(s16x8*)&V0l[o] = vl;
        *(s16x8*)&V1h[o] = th2; *(s16x8*)&V1l[o] = tl2;
    }
}

// ---------------------------------------------------------------------------
// Split-bf16 MFMA GEMM (proven round-7/8): C = alpha * A @ W (+bias).
// 128x128 tile, BK=32, 4 waves, 4x4 MFMA 16x16x32, async LDS staging.
// ---------------------------------------------------------------------------
__global__ __launch_bounds__(256, 2) void gemm_mfma(
    const u16* __restrict__ Ah, const u16* __restrict__ Al,
    const u16* __restrict__ Bh, const u16* __restrict__ Bl,
    u16* __restrict__ Ch, u16* __restrict__ Cl,
    const float* __restrict__ bias, const float alpha)
{
    __shared__ __align__(16) u16 lAh[128*32], lAl[128*32], lBh[128*32], lBl[128*32];
    const int t    = threadIdx.x;
    const int lane = t & 63;
    const int w    = t >> 6;
    const int wr = w >> 1, wc = w & 1;
    const int qd = lane >> 4, l15 = lane & 15;
    const int m0 = blockIdx.x * 128, n0 = blockIdx.y * 128;

    const int srow = t >> 2;
    const int skc  = (t & 3) * 8;

    f32x4 acc[4][4];
    const f32x4 z = {0.f, 0.f, 0.f, 0.f};
#pragma unroll
    for (int i = 0; i < 4; ++i)
#pragma unroll
        for (int j = 0; j < 4; ++j) acc[i][j] = z;

    for (int k0 = 0; k0 < NU; k0 += 32) {
#pragma unroll
        for (int half = 0; half < 2; ++half) {
            const int rr = srow + half*64;
            const size_t ga = (size_t)(m0 + rr)*NU + k0 + skc;
            const size_t gb = (size_t)(n0 + rr)*NU + k0 + skc;
            const int lo = rr*32 + skc;
            gl_lds16(Ah + ga, &lAh[lo]);
            gl_lds16(Al + ga, &lAl[lo]);
            gl_lds16(Bh + gb, &lBh[lo]);
            gl_lds16(Bl + gb, &lBl[lo]);
        }
        __syncthreads();

        s16x8 ah[4], al[4], bh[4], bl[4];
#pragma unroll
        for (int mt = 0; mt < 4; ++mt) {
            const int off = (wr*64 + mt*16 + l15)*32 + qd*8;
            ah[mt] = *(const s16x8*)&lAh[off];
            al[mt] = *(const s16x8*)&lAl[off];
        }
#pragma unroll
        for (int nt = 0; nt < 4; ++nt) {
            const int off = (wc*64 + nt*16 + l15)*32 + qd*8;
            bh[nt] = *(const s16x8*)&lBh[off];
            bl[nt] = *(const s16x8*)&lBl[off];
        }
#pragma unroll
        for (int mt = 0; mt < 4; ++mt)
#pragma unroll
            for (int nt = 0; nt < 4; ++nt) {
                acc[mt][nt] = __builtin_amdgcn_mfma_f32_16x16x32_bf16(ah[mt], bh[nt], acc[mt][nt], 0, 0, 0);
                acc[mt][nt] = __builtin_amdgcn_mfma_f32_16x16x32_bf16(ah[mt], bl[nt], acc[mt][nt], 0, 0, 0);
                acc[mt][nt] = __builtin_amdgcn_mfma_f32_16x16x32_bf16(al[mt], bh[nt], acc[mt][nt], 0, 0, 0);
            }
        __syncthreads();
    }

#pragma unroll
    for (int mt = 0; mt < 4; ++mt) {
#pragma unroll
        for (int nt = 0; nt < 4; ++nt) {
            const int col = n0 + wc*64 + nt*16 + l15;
            const float bb = bias ? bias[col] : 0.0f;
#pragma unroll
            for (int r = 0; r < 4; ++r) {
                const int row = m0 + wr*64 + mt*16 + qd*4 + r;
                const float v = alpha*acc[mt][nt][r] + bb;
                const u16 h  = f2bf(v);
                const u16 lo = f2bf(v - bf2f(h));
                const size_t o = (size_t)row*NU + col;
                Ch[o] = h; Cl[o] = lo;
            }
        }
    }
}

// ---------------------------------------------------------------------------
// out = V0 @ W_out + b_out, N=10. One wave per batch row; V0 from planes.
// ---------------------------------------------------------------------------
__global__ __launch_bounds__(256) void out_gemm(
    const u16* __restrict__ V0h, const u16* __restrict__ V0l,
    const float* __restrict__ Wout,
    const float* __restrict__ bout, float* __restrict__ out)
{
    __shared__ float Ws[NU*NDOUT];
    const int t = threadIdx.x;
    for (int i = t; i < NU*NDOUT; i += 256) Ws[i] = Wout[i];
    __syncthreads();
    const int lane = t & 63;
    const int wv = t >> 6;
    const int row = blockIdx.x*4 + wv;
    float acc[NDOUT];
#pragma unroll
    for (int j = 0; j < NDOUT; ++j) acc[j] = 0.0f;
#pragma unroll
    for (int s = 0; s < 4; ++s) {
        const int k = lane + 64*s;
        const size_t o = (size_t)row*NU + k;
        const float v = bf2f(V0h[o]) + bf2f(V0l[o]);
#pragma unroll
        for (int j = 0; j < NDOUT; ++j) acc[j] = fmaf(v, Ws[k*NDOUT + j], acc[j]);
    }
#pragma unroll
    for (int off = 32; off > 0; off >>= 1) {
#pragma unroll
        for (int j = 0; j < NDOUT; ++j) acc[j] += __shfl_down(acc[j], off);
    }
    if (lane == 0) {
#pragma unroll
        for (int j = 0; j < NDOUT; ++j) out[(size_t)row*NDOUT + j] = acc[j] + bout[j];
    }
}

extern "C" void kernel_launch(void* const* d_in, const int* in_sizes, int n_in,
                              void* d_out, int out_size, void* d_ws, size_t ws_size,
                              hipStream_t stream)
{
    const float* x    = (const float*)d_in[0];
    const float* Win  = (const float*)d_in[1];
    const float* bin  = (const float*)d_in[2];
    const float* B0   = (const float*)d_in[3];
    const float* q    = (const float*)d_in[4];
    const float* Wout = (const float*)d_in[5];
    const float* bout = (const float*)d_in[6];
    float* out = (float*)d_out;

    u16* wnnh = (u16*)d_ws;
    u16* wnnl = wnnh + (size_t)NLAYERS*NUSQ;
    u16* wnth = wnnl + (size_t)NLAYERS*NUSQ;
    u16* wntl = wnth + (size_t)NLAYERS*NUSQ;
    float* bq = (float*)(wntl + (size_t)NLAYERS*NUSQ);
    u16* pl   = (u16*)(bq + NLAYERS*NU);
    const size_t PSZ = (size_t)NBATCH*NU;
    u16* sAh = pl;           u16* sAl = sAh + PSZ;
    u16* sBh = sAl + PSZ;    u16* sBl = sBh + PSZ;
    u16* sCh = sBl + PSZ;    u16* sCl = sCh + PSZ;

    // fused: 6 invert blocks + 256 in_gemm blocks (512 threads each)
    fused_inv_ingemm<<<NLAYERS + 256, 512, 0, stream>>>(
        B0, q, wnnh, wnnl, wnth, wntl, bq,
        x, Win, bin, sAh, sAl, sBh, sBl);

    const dim3 ggrid(NBATCH/128, NU/128);   // 256 x 2

    u16 *v0h = sAh, *v0l = sAl, *v1h = sBh, *v1l = sBl, *frh = sCh, *frl = sCl;
    for (int l = 0; l < NLAYERS; ++l) {
        const size_t wo = (size_t)l*NUSQ;
        gemm_mfma<<<ggrid, 256, 0, stream>>>(v1h, v1l, wnnh + wo, wnnl + wo,
                                             frh, frl, nullptr, -1.0f);
        gemm_mfma<<<ggrid, 256, 0, stream>>>(v0h, v0l, wnth + wo, wntl + wo,
                                             v1h, v1l, bq + (size_t)l*NU, 1.0f);
        u16* t0 = v0h; u16* t1 = v0l;
        v0h = frh; v0l = frl; frh = t0; frl = t1;
    }
    out_gemm<<<NBATCH/4, 256, 0, stream>>>(v0h, v0l, Wout, bout, out);
}